// Round 2
// baseline (110.413 us; speedup 1.0000x reference)
//
#include <hip/hip_runtime.h>

#define TILE_ROWS 512
#define TILE_BYTES (TILE_ROWS * 40)      // 20480 B = 20 KiB LDS per block
#define CHUNKS_PER_WAVE 5                // 20480 / 1024 / 4 waves

// LUT = [0,0,1,1,1,1,1,1,0,0] -> binary label is 1 iff class in [2,7]
__device__ __forceinline__ int lut_of(int c) {
    return (c >= 2 && c <= 7) ? 1 : 0;
}

// First-max-preserving combine: on tie keep the lower index (jnp.argmax).
__device__ __forceinline__ void amax2(float va, int ia, float vb, int ib,
                                      float& vo, int& io) {
    const bool take_b = vb > va;
    vo = take_b ? vb : va;
    io = take_b ? ib : ia;
}

// Per-row: CE contribution (max + log(sum exp) - x[tgt]) and binary mismatch.
__device__ __forceinline__ void row_stats(const float r[10], int tgt,
                                          float& ce_acc, unsigned int& mm_acc) {
    // max+argmax via tree (short dependence chain), first-max on ties
    float m01, m23, m45, m67, m89, m03, m47, m07, m;
    int   i01, i23, i45, i67, i89, i03, i47, i07, am;
    amax2(r[0], 0, r[1], 1, m01, i01);
    amax2(r[2], 2, r[3], 3, m23, i23);
    amax2(r[4], 4, r[5], 5, m45, i45);
    amax2(r[6], 6, r[7], 7, m67, i67);
    amax2(r[8], 8, r[9], 9, m89, i89);
    amax2(m01, i01, m23, i23, m03, i03);
    amax2(m45, i45, m67, i67, m47, i47);
    amax2(m03, i03, m47, i47, m07, i07);
    amax2(m07, i07, m89, i89, m, am);

    // sum exp via pairwise tree
    float e0 = __expf(r[0] - m), e1 = __expf(r[1] - m);
    float e2 = __expf(r[2] - m), e3 = __expf(r[3] - m);
    float e4 = __expf(r[4] - m), e5 = __expf(r[5] - m);
    float e6 = __expf(r[6] - m), e7 = __expf(r[7] - m);
    float e8 = __expf(r[8] - m), e9 = __expf(r[9] - m);
    float se = (((e0 + e1) + (e2 + e3)) + ((e4 + e5) + (e6 + e7))) + (e8 + e9);

    // static-index select of r[tgt] (avoid runtime-indexed array -> scratch)
    float pt = r[0];
    #pragma unroll
    for (int j = 1; j < 10; ++j) pt = (tgt == j) ? r[j] : pt;

    ce_acc += m + __logf(se) - pt;
    mm_acc += (lut_of(am) != lut_of(tgt)) ? 1u : 0u;
}

__global__ void __launch_bounds__(256)
loss_tiled(const float* __restrict__ pred,
           const int* __restrict__ target,
           int nrows, int ntiles_full,
           float* __restrict__ ce_sum,
           unsigned int* __restrict__ mm_sum) {
    __shared__ float lds[TILE_ROWS * 10];

    float ce = 0.0f;
    unsigned int mm = 0u;

    const int bid = blockIdx.x;

    if (bid < ntiles_full) {
        // ---- coalesced global -> LDS staging (1 KiB per wave per instr) ----
        const int wid  = threadIdx.x >> 6;
        const int lane = threadIdx.x & 63;
        const char* src = (const char*)pred + (size_t)bid * TILE_BYTES;
        #pragma unroll
        for (int k = 0; k < CHUNKS_PER_WAVE; ++k) {
            const int off = (wid * CHUNKS_PER_WAVE + k) * 1024;
            __builtin_amdgcn_global_load_lds(
                (const __attribute__((address_space(1))) unsigned int*)(src + off + lane * 16),
                (__attribute__((address_space(3))) unsigned int*)((char*)lds + off),
                16, 0, 0);
        }
        __syncthreads();   // compiler drains vmcnt before the barrier

        const int row0 = bid * TILE_ROWS;
        #pragma unroll
        for (int rr = 0; rr < 2; ++rr) {
            const int r = threadIdx.x + rr * 256;
            const float2* rowp = (const float2*)(lds + r * 10);
            float2 a0 = rowp[0], a1 = rowp[1], a2 = rowp[2], a3 = rowp[3], a4 = rowp[4];
            const float f[10] = {a0.x, a0.y, a1.x, a1.y, a2.x,
                                 a2.y, a3.x, a3.y, a4.x, a4.y};
            row_stats(f, target[row0 + r], ce, mm);
        }
    } else {
        // ---- tail block: < TILE_ROWS leftover rows, direct global loads ----
        const int tail0 = ntiles_full * TILE_ROWS;
        #pragma unroll
        for (int rr = 0; rr < 2; ++rr) {
            const int row = tail0 + threadIdx.x + rr * 256;
            if (row < nrows) {
                const float2* rowp = (const float2*)(pred + (size_t)row * 10);
                float2 a0 = rowp[0], a1 = rowp[1], a2 = rowp[2], a3 = rowp[3], a4 = rowp[4];
                const float f[10] = {a0.x, a0.y, a1.x, a1.y, a2.x,
                                     a2.y, a3.x, a3.y, a4.x, a4.y};
                row_stats(f, target[row], ce, mm);
            }
        }
    }

    // ---- wave-64 reduction, then cross-wave via LDS, one atomic per block ----
    #pragma unroll
    for (int off = 32; off > 0; off >>= 1) {
        ce += __shfl_down(ce, off);
        mm += __shfl_down(mm, off);
    }

    __shared__ float        s_ce[4];
    __shared__ unsigned int s_mm[4];
    const int wid2  = threadIdx.x >> 6;
    const int lane2 = threadIdx.x & 63;
    if (lane2 == 0) { s_ce[wid2] = ce; s_mm[wid2] = mm; }
    __syncthreads();

    if (threadIdx.x == 0) {
        float        c = 0.0f;
        unsigned int t = 0u;
        #pragma unroll
        for (int w = 0; w < 4; ++w) { c += s_ce[w]; t += s_mm[w]; }
        atomicAdd(ce_sum, c);
        atomicAdd(mm_sum, t);
    }
}

__global__ void loss_finalize(const float* __restrict__ ce_sum,
                              const unsigned int* __restrict__ mm_sum,
                              float* __restrict__ out, float inv_n) {
    // ce mean + 100 * mismatch-rate (exact collapse of clamped-log BCE on {0,1})
    out[0] = ce_sum[0] * inv_n + 100.0f * (float)mm_sum[0] * inv_n;
}

extern "C" void kernel_launch(void* const* d_in, const int* in_sizes, int n_in,
                              void* d_out, int out_size, void* d_ws, size_t ws_size,
                              hipStream_t stream) {
    const float* pred   = (const float*)d_in[0];
    const int*   target = (const int*)d_in[1];

    const int nrows       = in_sizes[0] / 10;
    const int ntiles_full = nrows / TILE_ROWS;
    const int tail_rows   = nrows - ntiles_full * TILE_ROWS;

    float*        ws_ce = (float*)d_ws;
    unsigned int* ws_mm = (unsigned int*)((char*)d_ws + sizeof(float));

    // Zero accumulators every call (harness does not re-poison between replays).
    hipMemsetAsync(d_ws, 0, 2 * sizeof(unsigned int), stream);

    const int blocks = ntiles_full + (tail_rows ? 1 : 0);

    loss_tiled<<<blocks, 256, 0, stream>>>(pred, target, nrows, ntiles_full,
                                           ws_ce, ws_mm);
    loss_finalize<<<1, 1, 0, stream>>>(ws_ce, ws_mm, (float*)d_out,
                                       1.0f / (float)nrows);
}

// Round 3
// 109.932 us; speedup vs baseline: 1.0044x; 1.0044x over previous
//
#include <hip/hip_runtime.h>

#define ROWS_PER_WAVE   128
#define F4_PER_WAVE     (ROWS_PER_WAVE * 10 / 4)   // 320 float4 = 5120 B per region
#define WAVES_PER_BLOCK 4
#define SLICE_FLOATS    (ROWS_PER_WAVE * 10)       // 1280 floats per wave slice

// LUT = [0,0,1,1,1,1,1,1,0,0] -> binary label is 1 iff class in [2,7]
__device__ __forceinline__ int lut_of(int c) { return (c >= 2 && c <= 7) ? 1 : 0; }

// First-max-preserving combine (jnp.argmax: lowest index on ties).
__device__ __forceinline__ void amax2(float va, int ia, float vb, int ib,
                                      float& vo, int& io) {
    const bool tb = vb > va;
    vo = tb ? vb : va;
    io = tb ? ib : ia;
}

// Per-row: CE contribution (max + log(sum exp) - x[tgt]) and binary mismatch.
__device__ __forceinline__ void row_stats(const float r[10], int tgt,
                                          float& ce_acc, unsigned int& mm_acc) {
    float m01,m23,m45,m67,m89,m03,m47,m07,m;
    int   i01,i23,i45,i67,i89,i03,i47,i07,am;
    amax2(r[0],0,r[1],1,m01,i01);
    amax2(r[2],2,r[3],3,m23,i23);
    amax2(r[4],4,r[5],5,m45,i45);
    amax2(r[6],6,r[7],7,m67,i67);
    amax2(r[8],8,r[9],9,m89,i89);
    amax2(m01,i01,m23,i23,m03,i03);
    amax2(m45,i45,m67,i67,m47,i47);
    amax2(m03,i03,m47,i47,m07,i07);
    amax2(m07,i07,m89,i89,m,am);

    float e0=__expf(r[0]-m), e1=__expf(r[1]-m), e2=__expf(r[2]-m), e3=__expf(r[3]-m), e4=__expf(r[4]-m);
    float e5=__expf(r[5]-m), e6=__expf(r[6]-m), e7=__expf(r[7]-m), e8=__expf(r[8]-m), e9=__expf(r[9]-m);
    float se = (((e0+e1)+(e2+e3)) + ((e4+e5)+(e6+e7))) + (e8+e9);

    // static-index select of r[tgt] (rule #20: no runtime-indexed arrays)
    float pt = r[0];
    #pragma unroll
    for (int j = 1; j < 10; ++j) pt = (tgt == j) ? r[j] : pt;

    ce_acc += m + __logf(se) - pt;
    mm_acc += (lut_of(am) != lut_of(tgt)) ? 1u : 0u;
}

__global__ void __launch_bounds__(256)
loss_wave(const float* __restrict__ pred, const int* __restrict__ target,
          int nrows, int nregions_full, int total_regions,
          float* __restrict__ ce_sum, unsigned int* __restrict__ mm_sum) {
    // 4 private per-wave slices; no __syncthreads in the hot path.
    __shared__ float lds[WAVES_PER_BLOCK * SLICE_FLOATS];   // 20480 B exactly

    float ce = 0.0f;
    unsigned int mm = 0u;

    const int wid    = threadIdx.x >> 6;
    const int lane   = threadIdx.x & 63;
    const int region = blockIdx.x * WAVES_PER_BLOCK + wid;

    float* slice = lds + wid * SLICE_FLOATS;

    if (region < nregions_full) {
        // ---- m13-pattern: 5 lane-contiguous float4 loads (1 KiB/wave/instr) ----
        const float4* g = (const float4*)pred + (size_t)region * F4_PER_WAVE;
        float4 v0 = g[lane      ];
        float4 v1 = g[lane +  64];
        float4 v2 = g[lane + 128];
        float4 v3 = g[lane + 192];
        float4 v4 = g[lane + 256];

        const int grow = region * ROWS_PER_WAVE + 2 * lane;
        const int t0 = target[grow];
        const int t1 = target[grow + 1];

        // ---- per-wave LDS transpose: linear b128 writes ----
        float4* s4 = (float4*)slice;
        s4[lane      ] = v0;
        s4[lane +  64] = v1;
        s4[lane + 128] = v2;
        s4[lane + 192] = v3;
        s4[lane + 256] = v4;
        // wave-local ds_write -> ds_read ordering via compiler lgkmcnt (same wave)

        // ---- read back own 2 rows: 10x ds_read_b64, stride 40 B (4-way max) ----
        const float2* rp = (const float2*)(slice + 20 * lane);
        float2 a0=rp[0], a1=rp[1], a2=rp[2], a3=rp[3], a4=rp[4];   // row 2*lane
        float2 b0=rp[5], b1=rp[6], b2=rp[7], b3=rp[8], b4=rp[9];   // row 2*lane+1

        {
            const float f[10] = {a0.x,a0.y,a1.x,a1.y,a2.x,a2.y,a3.x,a3.y,a4.x,a4.y};
            row_stats(f, t0, ce, mm);
        }
        {
            const float f[10] = {b0.x,b0.y,b1.x,b1.y,b2.x,b2.y,b3.x,b3.y,b4.x,b4.y};
            row_stats(f, t1, ce, mm);
        }
    } else if (region < total_regions) {
        // ---- tail region (<128 rows): direct global reads, bounds-checked ----
        const int r0 = nregions_full * ROWS_PER_WAVE + 2 * lane;
        #pragma unroll
        for (int rr = 0; rr < 2; ++rr) {
            const int row = r0 + rr;
            if (row < nrows) {
                const float2* rowp = (const float2*)(pred + (size_t)row * 10);
                float2 a0=rowp[0], a1=rowp[1], a2=rowp[2], a3=rowp[3], a4=rowp[4];
                const float f[10] = {a0.x,a0.y,a1.x,a1.y,a2.x,a2.y,a3.x,a3.y,a4.x,a4.y};
                row_stats(f, target[row], ce, mm);
            }
        }
    }

    // ---- wave-64 reduction ----
    #pragma unroll
    for (int off = 32; off > 0; off >>= 1) {
        ce += __shfl_down(ce, off);
        mm += __shfl_down(mm, off);
    }

    // lane 0 parks its wave's partials in its OWN slice (already consumed),
    // so no extra LDS beyond the 20480 B buffer.
    if (lane == 0) {
        slice[0] = ce;
        ((unsigned int*)slice)[1] = mm;
    }
    __syncthreads();

    if (threadIdx.x == 0) {
        float        c = 0.0f;
        unsigned int t = 0u;
        #pragma unroll
        for (int w = 0; w < WAVES_PER_BLOCK; ++w) {
            c += lds[w * SLICE_FLOATS];
            t += ((const unsigned int*)lds)[w * SLICE_FLOATS + 1];
        }
        atomicAdd(ce_sum, c);
        atomicAdd(mm_sum, t);
    }
}

__global__ void loss_finalize(const float* __restrict__ ce_sum,
                              const unsigned int* __restrict__ mm_sum,
                              float* __restrict__ out, float inv_n) {
    // ce mean + 100 * mismatch-rate (exact collapse of clamped-log BCE on {0,1})
    out[0] = ce_sum[0] * inv_n + 100.0f * (float)mm_sum[0] * inv_n;
}

extern "C" void kernel_launch(void* const* d_in, const int* in_sizes, int n_in,
                              void* d_out, int out_size, void* d_ws, size_t ws_size,
                              hipStream_t stream) {
    const float* pred   = (const float*)d_in[0];
    const int*   target = (const int*)d_in[1];

    const int nrows         = in_sizes[0] / 10;
    const int nregions_full = nrows / ROWS_PER_WAVE;          // 15625 for N=2e6
    const int tail_rows     = nrows - nregions_full * ROWS_PER_WAVE;
    const int total_regions = nregions_full + (tail_rows ? 1 : 0);
    const int blocks        = (total_regions + WAVES_PER_BLOCK - 1) / WAVES_PER_BLOCK;

    float*        ws_ce = (float*)d_ws;
    unsigned int* ws_mm = (unsigned int*)((char*)d_ws + sizeof(float));

    // Zero accumulators every call (harness does not re-poison between replays).
    hipMemsetAsync(d_ws, 0, 2 * sizeof(unsigned int), stream);

    loss_wave<<<blocks, 256, 0, stream>>>(pred, target, nrows, nregions_full,
                                          total_regions, ws_ce, ws_mm);
    loss_finalize<<<1, 1, 0, stream>>>(ws_ce, ws_mm, (float*)d_out,
                                       1.0f / (float)nrows);
}

// Round 4
// 24.696 us; speedup vs baseline: 4.4708x; 4.4513x over previous
//
#include <hip/hip_runtime.h>

#define ROWS_PER_WAVE   128
#define F4_PER_WAVE     (ROWS_PER_WAVE * 10 / 4)   // 320 float4 = 5120 B per region
#define WAVES_PER_BLOCK 4
#define SLICE_FLOATS    (ROWS_PER_WAVE * 10)       // 1280 floats per wave slice

// LUT = [0,0,1,1,1,1,1,1,0,0] -> binary label is 1 iff class in [2,7]
__device__ __forceinline__ int lut_of(int c) { return (c >= 2 && c <= 7) ? 1 : 0; }

// First-max-preserving combine (jnp.argmax: lowest index on ties).
__device__ __forceinline__ void amax2(float va, int ia, float vb, int ib,
                                      float& vo, int& io) {
    const bool tb = vb > va;
    vo = tb ? vb : va;
    io = tb ? ib : ia;
}

// Per-row: CE contribution (max + log(sum exp) - x[tgt]) and binary mismatch.
__device__ __forceinline__ void row_stats(const float r[10], int tgt,
                                          float& ce_acc, float& mm_acc) {
    float m01,m23,m45,m67,m89,m03,m47,m07,m;
    int   i01,i23,i45,i67,i89,i03,i47,i07,am;
    amax2(r[0],0,r[1],1,m01,i01);
    amax2(r[2],2,r[3],3,m23,i23);
    amax2(r[4],4,r[5],5,m45,i45);
    amax2(r[6],6,r[7],7,m67,i67);
    amax2(r[8],8,r[9],9,m89,i89);
    amax2(m01,i01,m23,i23,m03,i03);
    amax2(m45,i45,m67,i67,m47,i47);
    amax2(m03,i03,m47,i47,m07,i07);
    amax2(m07,i07,m89,i89,m,am);

    float e0=__expf(r[0]-m), e1=__expf(r[1]-m), e2=__expf(r[2]-m), e3=__expf(r[3]-m), e4=__expf(r[4]-m);
    float e5=__expf(r[5]-m), e6=__expf(r[6]-m), e7=__expf(r[7]-m), e8=__expf(r[8]-m), e9=__expf(r[9]-m);
    float se = (((e0+e1)+(e2+e3)) + ((e4+e5)+(e6+e7))) + (e8+e9);

    // static-index select of r[tgt] (rule #20: no runtime-indexed arrays)
    float pt = r[0];
    #pragma unroll
    for (int j = 1; j < 10; ++j) pt = (tgt == j) ? r[j] : pt;

    ce_acc += m + __logf(se) - pt;
    mm_acc += (lut_of(am) != lut_of(tgt)) ? 1.0f : 0.0f;   // exact small ints in f32
}

__global__ void __launch_bounds__(256)
loss_wave(const float* __restrict__ pred, const int* __restrict__ target,
          int nrows, int nregions_full, int total_regions,
          float2* __restrict__ partials) {
    // 4 private per-wave slices; no __syncthreads in the hot path.
    __shared__ float lds[WAVES_PER_BLOCK * SLICE_FLOATS];   // 20480 B exactly

    float ce = 0.0f;
    float mm = 0.0f;

    const int wid    = threadIdx.x >> 6;
    const int lane   = threadIdx.x & 63;
    const int region = blockIdx.x * WAVES_PER_BLOCK + wid;

    float* slice = lds + wid * SLICE_FLOATS;

    if (region < nregions_full) {
        // ---- lane-contiguous float4 loads (1 KiB/wave/instr, m13 pattern) ----
        const float4* g = (const float4*)pred + (size_t)region * F4_PER_WAVE;
        float4 v0 = g[lane      ];
        float4 v1 = g[lane +  64];
        float4 v2 = g[lane + 128];
        float4 v3 = g[lane + 192];
        float4 v4 = g[lane + 256];

        const int grow = region * ROWS_PER_WAVE + 2 * lane;
        const int t0 = target[grow];
        const int t1 = target[grow + 1];

        // ---- per-wave LDS transpose: linear b128 writes ----
        float4* s4 = (float4*)slice;
        s4[lane      ] = v0;
        s4[lane +  64] = v1;
        s4[lane + 128] = v2;
        s4[lane + 192] = v3;
        s4[lane + 256] = v4;
        // wave-local ds_write -> ds_read ordering via compiler lgkmcnt (same wave)

        // ---- read back own 2 rows: 10x ds_read_b64, stride 40 B (<=4-way) ----
        const float2* rp = (const float2*)(slice + 20 * lane);
        float2 a0=rp[0], a1=rp[1], a2=rp[2], a3=rp[3], a4=rp[4];   // row 2*lane
        float2 b0=rp[5], b1=rp[6], b2=rp[7], b3=rp[8], b4=rp[9];   // row 2*lane+1

        {
            const float f[10] = {a0.x,a0.y,a1.x,a1.y,a2.x,a2.y,a3.x,a3.y,a4.x,a4.y};
            row_stats(f, t0, ce, mm);
        }
        {
            const float f[10] = {b0.x,b0.y,b1.x,b1.y,b2.x,b2.y,b3.x,b3.y,b4.x,b4.y};
            row_stats(f, t1, ce, mm);
        }
    } else if (region < total_regions) {
        // ---- tail region (<128 rows): direct global reads, bounds-checked ----
        const int r0 = nregions_full * ROWS_PER_WAVE + 2 * lane;
        #pragma unroll
        for (int rr = 0; rr < 2; ++rr) {
            const int row = r0 + rr;
            if (row < nrows) {
                const float2* rowp = (const float2*)(pred + (size_t)row * 10);
                float2 a0=rowp[0], a1=rowp[1], a2=rowp[2], a3=rowp[3], a4=rowp[4];
                const float f[10] = {a0.x,a0.y,a1.x,a1.y,a2.x,a2.y,a3.x,a3.y,a4.x,a4.y};
                row_stats(f, target[row], ce, mm);
            }
        }
    }

    // ---- wave-64 reduction ----
    #pragma unroll
    for (int off = 32; off > 0; off >>= 1) {
        ce += __shfl_down(ce, off);
        mm += __shfl_down(mm, off);
    }

    // lane 0 parks partials in its OWN (already-consumed) slice
    if (lane == 0) {
        slice[0] = ce;
        slice[1] = mm;
    }
    __syncthreads();

    // ---- NO atomics: one plain 8B store per block (contention-free) ----
    if (threadIdx.x == 0) {
        float c = 0.0f, t = 0.0f;
        #pragma unroll
        for (int w = 0; w < WAVES_PER_BLOCK; ++w) {
            c += lds[w * SLICE_FLOATS];
            t += lds[w * SLICE_FLOATS + 1];
        }
        partials[blockIdx.x] = make_float2(c, t);
    }
}

__global__ void __launch_bounds__(256)
loss_reduce(const float2* __restrict__ partials, int nparts,
            float* __restrict__ out, float inv_n) {
    __shared__ float s_ce[4], s_mm[4];
    float ce = 0.0f, mm = 0.0f;

    for (int i = threadIdx.x; i < nparts; i += 256) {
        float2 p = partials[i];
        ce += p.x;
        mm += p.y;
    }
    #pragma unroll
    for (int off = 32; off > 0; off >>= 1) {
        ce += __shfl_down(ce, off);
        mm += __shfl_down(mm, off);
    }
    const int wid  = threadIdx.x >> 6;
    const int lane = threadIdx.x & 63;
    if (lane == 0) { s_ce[wid] = ce; s_mm[wid] = mm; }
    __syncthreads();
    if (threadIdx.x == 0) {
        float c = s_ce[0] + s_ce[1] + s_ce[2] + s_ce[3];
        float t = s_mm[0] + s_mm[1] + s_mm[2] + s_mm[3];
        // ce mean + 100 * mismatch-rate (exact collapse of clamped-log BCE on {0,1})
        out[0] = c * inv_n + 100.0f * t * inv_n;
    }
}

extern "C" void kernel_launch(void* const* d_in, const int* in_sizes, int n_in,
                              void* d_out, int out_size, void* d_ws, size_t ws_size,
                              hipStream_t stream) {
    const float* pred   = (const float*)d_in[0];
    const int*   target = (const int*)d_in[1];

    const int nrows         = in_sizes[0] / 10;
    const int nregions_full = nrows / ROWS_PER_WAVE;          // 15625 for N=2e6
    const int tail_rows     = nrows - nregions_full * ROWS_PER_WAVE;
    const int total_regions = nregions_full + (tail_rows ? 1 : 0);
    const int blocks        = (total_regions + WAVES_PER_BLOCK - 1) / WAVES_PER_BLOCK;

    float2* partials = (float2*)d_ws;   // blocks * 8 B, overwritten every call

    loss_wave<<<blocks, 256, 0, stream>>>(pred, target, nrows, nregions_full,
                                          total_regions, partials);
    loss_reduce<<<1, 256, 0, stream>>>(partials, blocks, (float*)d_out,
                                       1.0f / (float)nrows);
}

// Round 5
// 23.073 us; speedup vs baseline: 4.7854x; 1.0704x over previous
//
#include <hip/hip_runtime.h>

#define ROWS_PER_WAVE   128
#define F4_PER_WAVE     (ROWS_PER_WAVE * 10 / 4)   // 320 float4 = 5120 B per region
#define WAVES_PER_BLOCK 4
#define SLICE_FLOATS    (ROWS_PER_WAVE * 10)       // 1280 floats per wave slice
#define MAX_BLOCKS      2048                       // 8 blocks/CU x 256 CU

// LUT = [0,0,1,1,1,1,1,1,0,0] -> binary label is 1 iff class in [2,7]
__device__ __forceinline__ int lut_of(int c) { return (c >= 2 && c <= 7) ? 1 : 0; }

// First-max-preserving combine (jnp.argmax: lowest index on ties).
__device__ __forceinline__ void amax2(float va, int ia, float vb, int ib,
                                      float& vo, int& io) {
    const bool tb = vb > va;
    vo = tb ? vb : va;
    io = tb ? ib : ia;
}

// Per-row: CE contribution (max + log(sum exp) - x[tgt]) and binary mismatch.
__device__ __forceinline__ void row_stats(const float r[10], int tgt,
                                          float& ce_acc, float& mm_acc) {
    float m01,m23,m45,m67,m89,m03,m47,m07,m;
    int   i01,i23,i45,i67,i89,i03,i47,i07,am;
    amax2(r[0],0,r[1],1,m01,i01);
    amax2(r[2],2,r[3],3,m23,i23);
    amax2(r[4],4,r[5],5,m45,i45);
    amax2(r[6],6,r[7],7,m67,i67);
    amax2(r[8],8,r[9],9,m89,i89);
    amax2(m01,i01,m23,i23,m03,i03);
    amax2(m45,i45,m67,i67,m47,i47);
    amax2(m03,i03,m47,i47,m07,i07);
    amax2(m07,i07,m89,i89,m,am);

    float e0=__expf(r[0]-m), e1=__expf(r[1]-m), e2=__expf(r[2]-m), e3=__expf(r[3]-m), e4=__expf(r[4]-m);
    float e5=__expf(r[5]-m), e6=__expf(r[6]-m), e7=__expf(r[7]-m), e8=__expf(r[8]-m), e9=__expf(r[9]-m);
    float se = (((e0+e1)+(e2+e3)) + ((e4+e5)+(e6+e7))) + (e8+e9);

    // static-index select of r[tgt] (rule #20: no runtime-indexed arrays)
    float pt = r[0];
    #pragma unroll
    for (int j = 1; j < 10; ++j) pt = (tgt == j) ? r[j] : pt;

    ce_acc += m + __logf(se) - pt;
    mm_acc += (lut_of(am) != lut_of(tgt)) ? 1.0f : 0.0f;   // exact small ints in f32
}

__global__ void __launch_bounds__(256)
loss_wave(const float* __restrict__ pred, const int* __restrict__ target,
          int nrows, int nregions_full, int total_regions, int nwaves,
          float2* __restrict__ partials) {
    // 4 private per-wave slices; no __syncthreads in the hot path.
    __shared__ float lds[WAVES_PER_BLOCK * SLICE_FLOATS];   // 20480 B exactly

    float ce = 0.0f;
    float mm = 0.0f;

    const int wid  = threadIdx.x >> 6;
    const int lane = threadIdx.x & 63;
    const int wave = blockIdx.x * WAVES_PER_BLOCK + wid;

    float* slice = lds + wid * SLICE_FLOATS;
    float4* s4 = (float4*)slice;

    // ---- persistent-wave grid-stride over regions ----
    for (int region = wave; region < total_regions; region += nwaves) {
        if (region < nregions_full) {
            // lane-contiguous float4 loads (1 KiB/wave/instr, m13 pattern)
            const float4* g = (const float4*)pred + (size_t)region * F4_PER_WAVE;
            float4 v0 = g[lane      ];
            float4 v1 = g[lane +  64];
            float4 v2 = g[lane + 128];
            float4 v3 = g[lane + 192];
            float4 v4 = g[lane + 256];

            const int grow = region * ROWS_PER_WAVE + 2 * lane;
            const int t0 = target[grow];
            const int t1 = target[grow + 1];

            // per-wave LDS transpose: linear b128 writes (wave-local lgkmcnt order)
            s4[lane      ] = v0;
            s4[lane +  64] = v1;
            s4[lane + 128] = v2;
            s4[lane + 192] = v3;
            s4[lane + 256] = v4;

            // read back own 2 rows: 10x ds_read_b64, stride 40 B (<=4-way)
            const float2* rp = (const float2*)(slice + 20 * lane);
            float2 a0=rp[0], a1=rp[1], a2=rp[2], a3=rp[3], a4=rp[4];   // row 2*lane
            float2 b0=rp[5], b1=rp[6], b2=rp[7], b3=rp[8], b4=rp[9];   // row 2*lane+1

            {
                const float f[10] = {a0.x,a0.y,a1.x,a1.y,a2.x,a2.y,a3.x,a3.y,a4.x,a4.y};
                row_stats(f, t0, ce, mm);
            }
            {
                const float f[10] = {b0.x,b0.y,b1.x,b1.y,b2.x,b2.y,b3.x,b3.y,b4.x,b4.y};
                row_stats(f, t1, ce, mm);
            }
        } else {
            // tail region (<128 rows): direct global reads, bounds-checked
            const int r0 = nregions_full * ROWS_PER_WAVE + 2 * lane;
            #pragma unroll
            for (int rr = 0; rr < 2; ++rr) {
                const int row = r0 + rr;
                if (row < nrows) {
                    const float2* rowp = (const float2*)(pred + (size_t)row * 10);
                    float2 a0=rowp[0], a1=rowp[1], a2=rowp[2], a3=rowp[3], a4=rowp[4];
                    const float f[10] = {a0.x,a0.y,a1.x,a1.y,a2.x,a2.y,a3.x,a3.y,a4.x,a4.y};
                    row_stats(f, target[row], ce, mm);
                }
            }
        }
    }

    // ---- wave-64 reduction ----
    #pragma unroll
    for (int off = 32; off > 0; off >>= 1) {
        ce += __shfl_down(ce, off);
        mm += __shfl_down(mm, off);
    }

    // lane 0 parks partials in its OWN (already-consumed) slice
    if (lane == 0) {
        slice[0] = ce;
        slice[1] = mm;
    }
    __syncthreads();

    // ---- NO atomics: one plain 8B store per block (contention-free) ----
    if (threadIdx.x == 0) {
        float c = 0.0f, t = 0.0f;
        #pragma unroll
        for (int w = 0; w < WAVES_PER_BLOCK; ++w) {
            c += lds[w * SLICE_FLOATS];
            t += lds[w * SLICE_FLOATS + 1];
        }
        partials[blockIdx.x] = make_float2(c, t);
    }
}

__global__ void __launch_bounds__(256)
loss_reduce(const float2* __restrict__ partials, int nparts,
            float* __restrict__ out, float inv_n) {
    __shared__ float s_ce[4], s_mm[4];
    float ce = 0.0f, mm = 0.0f;

    for (int i = threadIdx.x; i < nparts; i += 256) {
        float2 p = partials[i];
        ce += p.x;
        mm += p.y;
    }
    #pragma unroll
    for (int off = 32; off > 0; off >>= 1) {
        ce += __shfl_down(ce, off);
        mm += __shfl_down(mm, off);
    }
    const int wid  = threadIdx.x >> 6;
    const int lane = threadIdx.x & 63;
    if (lane == 0) { s_ce[wid] = ce; s_mm[wid] = mm; }
    __syncthreads();
    if (threadIdx.x == 0) {
        float c = s_ce[0] + s_ce[1] + s_ce[2] + s_ce[3];
        float t = s_mm[0] + s_mm[1] + s_mm[2] + s_mm[3];
        // ce mean + 100 * mismatch-rate (exact collapse of clamped-log BCE on {0,1})
        out[0] = c * inv_n + 100.0f * t * inv_n;
    }
}

extern "C" void kernel_launch(void* const* d_in, const int* in_sizes, int n_in,
                              void* d_out, int out_size, void* d_ws, size_t ws_size,
                              hipStream_t stream) {
    const float* pred   = (const float*)d_in[0];
    const int*   target = (const int*)d_in[1];

    const int nrows         = in_sizes[0] / 10;
    const int nregions_full = nrows / ROWS_PER_WAVE;          // 15625 for N=2e6
    const int tail_rows     = nrows - nregions_full * ROWS_PER_WAVE;
    const int total_regions = nregions_full + (tail_rows ? 1 : 0);

    int blocks = (total_regions + WAVES_PER_BLOCK - 1) / WAVES_PER_BLOCK;
    if (blocks > MAX_BLOCKS) blocks = MAX_BLOCKS;
    const int nwaves = blocks * WAVES_PER_BLOCK;

    float2* partials = (float2*)d_ws;   // blocks * 8 B, overwritten every call

    loss_wave<<<blocks, 256, 0, stream>>>(pred, target, nrows, nregions_full,
                                          total_regions, nwaves, partials);
    loss_reduce<<<1, 256, 0, stream>>>(partials, blocks, (float*)d_out,
                                       1.0f / (float)nrows);
}